// Round 4
// baseline (190.103 us; speedup 1.0000x reference)
//
#include <hip/hip_runtime.h>

#define BB  4
#define LL  512
#define HID 256
#define PAi 32
#define OO  64

using bf16x8 = __attribute__((ext_vector_type(8))) short;
using f32x4  = __attribute__((ext_vector_type(4))) float;

__device__ inline ushort f2bf(float x) {
    union { float f; unsigned u; } v; v.f = x;
    unsigned r = (v.u + 0x7fff + ((v.u >> 16) & 1)) >> 16;  // RNE
    return (ushort)r;
}

// -------- Kernel 1: h[b,l,p] = dot(hidden[b,l,:], W_in[p,:]) + b_in[p]; f32 + bf16 copies --------
__global__ __launch_bounds__(256) void k_in(const float* __restrict__ hidden,
                                            const float* __restrict__ W_in,
                                            const float* __restrict__ b_in,
                                            float* __restrict__ h,
                                            ushort* __restrict__ hb) {
    __shared__ float4 hid[8 * 64];  // 8 rows x 256 floats = 8 KB
    const int tid  = threadIdx.x;
    const int row0 = blockIdx.x * 8;  // row in [0, B*L)
    const float4* src = (const float4*)(hidden + (size_t)row0 * HID);
    hid[tid]       = src[tid];
    hid[tid + 256] = src[tid + 256];
    __syncthreads();
    const int p = tid & 31;
    const int r = tid >> 5;
    const float4* w = (const float4*)(W_in + (size_t)p * HID);
    float acc = 0.f;
#pragma unroll
    for (int k = 0; k < 64; ++k) {
        float4 hv = hid[r * 64 + k];
        float4 wv = w[k];
        acc += hv.x * wv.x + hv.y * wv.y + hv.z * wv.z + hv.w * wv.w;
    }
    const float val = acc + b_in[p];
    h[(size_t)(row0 + r) * PAi + p]  = val;
    hb[(size_t)(row0 + r) * PAi + p] = f2bf(val);
}

// -------- Kernel 2: t[b,j,o,q] = sum_p h[b,j,p] * W_out[o, p*32+q]  (bf16 out) --------
// 16 rows per block -> W_out read once per 16 rows (32 MB total L2 traffic).
#define RMID 16
__global__ __launch_bounds__(256) void k_mid(const float* __restrict__ h,
                                             const float* __restrict__ W_out,
                                             ushort* __restrict__ t) {
    __shared__ __attribute__((aligned(16))) float hst[PAi][RMID];  // [p][r]
    const int tid  = threadIdx.x;
    const int row0 = blockIdx.x * RMID;
    for (int s = tid; s < RMID * PAi; s += 256) {
        const int r = s >> 5, p = s & 31;
        hst[p][r] = h[(size_t)(row0 + r) * PAi + p];
    }
    __syncthreads();
    const int qg = tid & 7;
    const int o1 = tid >> 3;  // 0..31
    const float4* W4 = (const float4*)W_out;  // [O][PA][8] float4
    float4 accA[RMID], accB[RMID];
#pragma unroll
    for (int r = 0; r < RMID; ++r) {
        accA[r] = float4{0, 0, 0, 0};
        accB[r] = float4{0, 0, 0, 0};
    }
#pragma unroll 2
    for (int p = 0; p < PAi; ++p) {
        const float4 wa = W4[(o1 * PAi + p) * 8 + qg];
        const float4 wb = W4[((o1 + 32) * PAi + p) * 8 + qg];
#pragma unroll
        for (int r4 = 0; r4 < RMID / 4; ++r4) {
            const float4 h4 = *(const float4*)&hst[p][r4 * 4];
            const float hr[4] = {h4.x, h4.y, h4.z, h4.w};
#pragma unroll
            for (int e = 0; e < 4; ++e) {
                const int r = r4 * 4 + e;
                accA[r].x += hr[e] * wa.x; accA[r].y += hr[e] * wa.y;
                accA[r].z += hr[e] * wa.z; accA[r].w += hr[e] * wa.w;
                accB[r].x += hr[e] * wb.x; accB[r].y += hr[e] * wb.y;
                accB[r].z += hr[e] * wb.z; accB[r].w += hr[e] * wb.w;
            }
        }
    }
#pragma unroll
    for (int r = 0; r < RMID; ++r) {
        ushort4 ua, ub;
        ua.x = f2bf(accA[r].x); ua.y = f2bf(accA[r].y); ua.z = f2bf(accA[r].z); ua.w = f2bf(accA[r].w);
        ub.x = f2bf(accB[r].x); ub.y = f2bf(accB[r].y); ub.z = f2bf(accB[r].z); ub.w = f2bf(accB[r].w);
        ushort* dst = t + (size_t)(row0 + r) * OO * PAi;
        *(ushort4*)(dst + (o1 * 8 + qg) * 4)        = ua;
        *(ushort4*)(dst + ((o1 + 32) * 8 + qg) * 4) = ub;
    }
}

// -------- Kernel 3: out[b,i,jo] = sum_q t[b,jo,q]*h[b,i,q] + b_out[jo&63] + pw  (MFMA bf16) --------
// SWAPPED operands: A = t (m = jo_local), B = h (n = i_local). C/D: lane l, reg r ->
// D[row=(l>>4)*4+r][col=l&15] = out[jo0+tt*16+g*4+r][i0+l15]  => 4 consecutive jo per lane
// => float4 pw loads / out stores. MI=2 i-tiles per block amortize the t-fragment load.
#define NT 8
#define MI 2
__global__ __launch_bounds__(256) void k_out(const ushort* __restrict__ t,   // bf16 [B][L*OO][PAi]
                                             const ushort* __restrict__ hb,  // bf16 [B][L][PAi]
                                             const float* __restrict__ pw,
                                             const float* __restrict__ b_out,
                                             float* __restrict__ out) {
    const int tid  = threadIdx.x;
    const int lane = tid & 63;
    const int wave = tid >> 6;
    const int b    = blockIdx.z;
    const int i0   = blockIdx.y * (16 * MI);
    const int jo0  = blockIdx.x * (NT * 16 * 4) + wave * (NT * 16);  // multiple of 128
    const int l15  = lane & 15;
    const int g    = lane >> 4;  // 0..3

    bf16x8 hfrag[MI];
#pragma unroll
    for (int m = 0; m < MI; ++m)
        hfrag[m] = *(const bf16x8*)(hb + ((size_t)(b * LL + i0 + m * 16 + l15)) * PAi + g * 8);

    const ushort* tbase = t + ((size_t)b * LL * OO + jo0 + l15) * PAi + g * 8;
    size_t rowbase[MI];
#pragma unroll
    for (int m = 0; m < MI; ++m)
        rowbase[m] = ((size_t)(b * LL + i0 + m * 16 + l15)) * (LL * OO) + jo0 + g * 4;

#pragma unroll
    for (int tt = 0; tt < NT; ++tt) {
        const bf16x8 tfrag = *(const bf16x8*)(tbase + (size_t)tt * (16 * PAi));
        const float4 bo4 = *(const float4*)(b_out + ((tt * 16 + g * 4) & 63));
#pragma unroll
        for (int m = 0; m < MI; ++m) {
            f32x4 acc = {0.f, 0.f, 0.f, 0.f};
            acc = __builtin_amdgcn_mfma_f32_16x16x32_bf16(tfrag, hfrag[m], acc, 0, 0, 0);
            const size_t a = rowbase[m] + tt * 16;
            const float4 pv = *(const float4*)(pw + a);
            float4 res;
            res.x = acc[0] + bo4.x + pv.x;
            res.y = acc[1] + bo4.y + pv.y;
            res.z = acc[2] + bo4.z + pv.z;
            res.w = acc[3] + bo4.w + pv.w;
            *(float4*)(out + a) = res;
        }
    }
}

extern "C" void kernel_launch(void* const* d_in, const int* in_sizes, int n_in,
                              void* d_out, int out_size, void* d_ws, size_t ws_size,
                              hipStream_t stream) {
    const float* hidden = (const float*)d_in[0];
    const float* pw     = (const float*)d_in[1];
    const float* W_in   = (const float*)d_in[2];
    const float* b_in   = (const float*)d_in[3];
    const float* W_out  = (const float*)d_in[4];
    const float* b_out  = (const float*)d_in[5];
    float* out = (float*)d_out;

    float*  h  = (float*)d_ws;                                // 65536 f32  (256 KB)
    ushort* hb = (ushort*)(h + (size_t)BB * LL * PAi);        // 65536 bf16 (128 KB)
    ushort* tb = hb + (size_t)BB * LL * PAi;                  // 4194304 bf16 (8 MB)

    k_in <<<dim3(BB * LL / 8), 256, 0, stream>>>(hidden, W_in, b_in, h, hb);
    k_mid<<<dim3(BB * LL / RMID), 256, 0, stream>>>(h, W_out, tb);
    k_out<<<dim3(LL * OO / (NT * 16 * 4), LL / (16 * MI), BB), 256, 0, stream>>>(tb, hb, pw, b_out, out);
}

// Round 5
// 144.195 us; speedup vs baseline: 1.3184x; 1.3184x over previous
//
#include <hip/hip_runtime.h>

#define BB  4
#define LL  512
#define HID 256
#define PAi 32
#define OO  64

using bf16x8 = __attribute__((ext_vector_type(8))) short;
using f32x4  = __attribute__((ext_vector_type(4))) float;

__device__ inline ushort f2bf(float x) {
    union { float f; unsigned u; } v; v.f = x;
    unsigned r = (v.u + 0x7fff + ((v.u >> 16) & 1)) >> 16;  // RNE
    return (ushort)r;
}

// -------- Kernel 1: h[b,l,p] = dot(hidden[b,l,:], W_in[p,:]) + b_in[p]; f32 + bf16 copies --------
__global__ __launch_bounds__(256) void k_in(const float* __restrict__ hidden,
                                            const float* __restrict__ W_in,
                                            const float* __restrict__ b_in,
                                            float* __restrict__ h,
                                            ushort* __restrict__ hb) {
    __shared__ float4 hid[8 * 64];
    const int tid  = threadIdx.x;
    const int row0 = blockIdx.x * 8;
    const float4* src = (const float4*)(hidden + (size_t)row0 * HID);
    hid[tid]       = src[tid];
    hid[tid + 256] = src[tid + 256];
    __syncthreads();
    const int p = tid & 31;
    const int r = tid >> 5;
    const float4* w = (const float4*)(W_in + (size_t)p * HID);
    float acc = 0.f;
#pragma unroll
    for (int k = 0; k < 64; ++k) {
        float4 hv = hid[r * 64 + k];
        float4 wv = w[k];
        acc += hv.x * wv.x + hv.y * wv.y + hv.z * wv.z + hv.w * wv.w;
    }
    const float val = acc + b_in[p];
    h[(size_t)(row0 + r) * PAi + p]  = val;
    hb[(size_t)(row0 + r) * PAi + p] = f2bf(val);
}

// -------- Kernel 2: t[b,j,o,q] = sum_p h[b,j,p] * W_out[o, p*32+q]  (bf16 out) --------
#define RMID 16
__global__ __launch_bounds__(256) void k_mid(const float* __restrict__ h,
                                             const float* __restrict__ W_out,
                                             ushort* __restrict__ t) {
    __shared__ __attribute__((aligned(16))) float hst[PAi][RMID];
    const int tid  = threadIdx.x;
    const int row0 = blockIdx.x * RMID;
    for (int s = tid; s < RMID * PAi; s += 256) {
        const int r = s >> 5, p = s & 31;
        hst[p][r] = h[(size_t)(row0 + r) * PAi + p];
    }
    __syncthreads();
    const int qg = tid & 7;
    const int o1 = tid >> 3;
    const float4* W4 = (const float4*)W_out;
    float4 accA[RMID], accB[RMID];
#pragma unroll
    for (int r = 0; r < RMID; ++r) {
        accA[r] = float4{0, 0, 0, 0};
        accB[r] = float4{0, 0, 0, 0};
    }
#pragma unroll 2
    for (int p = 0; p < PAi; ++p) {
        const float4 wa = W4[(o1 * PAi + p) * 8 + qg];
        const float4 wb = W4[((o1 + 32) * PAi + p) * 8 + qg];
#pragma unroll
        for (int r4 = 0; r4 < RMID / 4; ++r4) {
            const float4 h4 = *(const float4*)&hst[p][r4 * 4];
            const float hr[4] = {h4.x, h4.y, h4.z, h4.w};
#pragma unroll
            for (int e = 0; e < 4; ++e) {
                const int r = r4 * 4 + e;
                accA[r].x += hr[e] * wa.x; accA[r].y += hr[e] * wa.y;
                accA[r].z += hr[e] * wa.z; accA[r].w += hr[e] * wa.w;
                accB[r].x += hr[e] * wb.x; accB[r].y += hr[e] * wb.y;
                accB[r].z += hr[e] * wb.z; accB[r].w += hr[e] * wb.w;
            }
        }
    }
#pragma unroll
    for (int r = 0; r < RMID; ++r) {
        ushort4 ua, ub;
        ua.x = f2bf(accA[r].x); ua.y = f2bf(accA[r].y); ua.z = f2bf(accA[r].z); ua.w = f2bf(accA[r].w);
        ub.x = f2bf(accB[r].x); ub.y = f2bf(accB[r].y); ub.z = f2bf(accB[r].z); ub.w = f2bf(accB[r].w);
        ushort* dst = t + (size_t)(row0 + r) * OO * PAi;
        *(ushort4*)(dst + (o1 * 8 + qg) * 4)        = ua;
        *(ushort4*)(dst + ((o1 + 32) * 8 + qg) * 4) = ub;
    }
}

// -------- Kernel 3: MFMA + LDS-transpose epilogue --------
// Per chunk of 512 jo: 4 waves x 8 MFMA (A = t rows [jo], B = h cols [i]) -> LDS [16 i][516],
// barrier, then each wave streams whole i-rows: 64 lanes x float4 = 1 KB contiguous per
// pw-load / out-store instruction. pw for the chunk is prefetched before the MFMA phase.
#define SEG 4096
#define CH  512
#define NCH (SEG / CH)
#define LSTR 516
__global__ __launch_bounds__(256) void k_out(const ushort* __restrict__ t,   // bf16 [B][L*OO][PAi]
                                             const ushort* __restrict__ hb,  // bf16 [B][L][PAi]
                                             const float* __restrict__ pw,
                                             const float* __restrict__ b_out,
                                             float* __restrict__ out) {
    __shared__ float sacc[16 * LSTR];  // 33 KB
    const int tid  = threadIdx.x;
    const int lane = tid & 63;
    const int wave = tid >> 6;
    const int b    = blockIdx.z;
    const int i0   = blockIdx.y * 16;
    const int seg0 = blockIdx.x * SEG;
    const int l15  = lane & 15;
    const int g    = lane >> 4;

    // B operand: h rows i0..i0+15 (n = l15, k = g*8+e)
    const bf16x8 hfrag = *(const bf16x8*)(hb + ((size_t)(b * LL + i0 + l15)) * PAi + g * 8);
    // bias for the streaming phase: col pattern (lane*4) & 63, row-independent
    const float4 bo4 = *(const float4*)(b_out + ((lane * 4) & 63));

    const size_t outrow0 = ((size_t)(b * LL + i0)) * (LL * OO);

    for (int c = 0; c < NCH; ++c) {
        const int cbase = seg0 + c * CH;

        // ---- prefetch pw for this chunk (independent float4s -> deep ILP) ----
        float4 pv[8];
#pragma unroll
        for (int rr = 0; rr < 4; ++rr) {
            const int row = wave * 4 + rr;
            const size_t gb = outrow0 + (size_t)row * (LL * OO) + cbase + lane * 4;
            pv[rr * 2]     = *(const float4*)(pw + gb);
            pv[rr * 2 + 1] = *(const float4*)(pw + gb + 256);
        }

        // ---- MFMA phase: wave's 128-jo strip ----
        const int wjo = cbase + wave * 128;
        const ushort* tb0 = t + ((size_t)b * LL * OO + wjo + l15) * PAi + g * 8;
        f32x4 acc[8];
#pragma unroll
        for (int tt = 0; tt < 8; ++tt) {
            const bf16x8 tfrag = *(const bf16x8*)(tb0 + (size_t)tt * (16 * PAi));
            f32x4 z = {0.f, 0.f, 0.f, 0.f};
            acc[tt] = __builtin_amdgcn_mfma_f32_16x16x32_bf16(tfrag, hfrag, z, 0, 0, 0);
        }
        // D[row=g*4+r][col=l15]: jo_local = g*4+r (+tt*16), i_local = l15
#pragma unroll
        for (int tt = 0; tt < 8; ++tt)
            *(f32x4*)&sacc[l15 * LSTR + wave * 128 + tt * 16 + g * 4] = acc[tt];
        __syncthreads();

        // ---- streaming phase: wave owns i-rows wave*4 .. wave*4+3 ----
#pragma unroll
        for (int rr = 0; rr < 4; ++rr) {
            const int row = wave * 4 + rr;
            const size_t gb = outrow0 + (size_t)row * (LL * OO) + cbase + lane * 4;
#pragma unroll
            for (int it = 0; it < 2; ++it) {
                const float4 a4 = *(const float4*)&sacc[row * LSTR + it * 256 + lane * 4];
                const float4 pvv = pv[rr * 2 + it];
                float4 res;
                res.x = a4.x + bo4.x + pvv.x;
                res.y = a4.y + bo4.y + pvv.y;
                res.z = a4.z + bo4.z + pvv.z;
                res.w = a4.w + bo4.w + pvv.w;
                *(float4*)(out + gb + it * 256) = res;
            }
        }
        __syncthreads();
    }
}

extern "C" void kernel_launch(void* const* d_in, const int* in_sizes, int n_in,
                              void* d_out, int out_size, void* d_ws, size_t ws_size,
                              hipStream_t stream) {
    const float* hidden = (const float*)d_in[0];
    const float* pw     = (const float*)d_in[1];
    const float* W_in   = (const float*)d_in[2];
    const float* b_in   = (const float*)d_in[3];
    const float* W_out  = (const float*)d_in[4];
    const float* b_out  = (const float*)d_in[5];
    float* out = (float*)d_out;

    float*  h  = (float*)d_ws;                                // 65536 f32  (256 KB)
    ushort* hb = (ushort*)(h + (size_t)BB * LL * PAi);        // 65536 bf16 (128 KB)
    ushort* tb = hb + (size_t)BB * LL * PAi;                  // 4194304 bf16 (8 MB)

    k_in <<<dim3(BB * LL / 8), 256, 0, stream>>>(hidden, W_in, b_in, h, hb);
    k_mid<<<dim3(BB * LL / RMID), 256, 0, stream>>>(h, W_out, tb);
    // grid: 8 jo-segments x 32 i-tiles x B = 1024 blocks (4/CU, LDS-limited fit)
    k_out<<<dim3(LL * OO / SEG, LL / 16, BB), 256, 0, stream>>>(tb, hb, pw, b_out, out);
}

// Round 7
// 131.414 us; speedup vs baseline: 1.4466x; 1.0973x over previous
//
#include <hip/hip_runtime.h>

#define BB  4
#define LL  512
#define HID 256
#define PAi 32
#define OO  64

using bf16x8 = __attribute__((ext_vector_type(8))) short;
using f32x4  = __attribute__((ext_vector_type(4))) float;

__device__ inline ushort f2bf(float x) {
    union { float f; unsigned u; } v; v.f = x;
    unsigned r = (v.u + 0x7fff + ((v.u >> 16) & 1)) >> 16;  // RNE
    return (ushort)r;
}

// -------- Kernel 1: h[b,l,p] = dot(hidden[b,l,:], W_in[p,:]) + b_in[p]; f32 + bf16 copies --------
__global__ __launch_bounds__(256) void k_in(const float* __restrict__ hidden,
                                            const float* __restrict__ W_in,
                                            const float* __restrict__ b_in,
                                            float* __restrict__ h,
                                            ushort* __restrict__ hb) {
    __shared__ float4 hid[8 * 64];
    const int tid  = threadIdx.x;
    const int row0 = blockIdx.x * 8;
    const float4* src = (const float4*)(hidden + (size_t)row0 * HID);
    hid[tid]       = src[tid];
    hid[tid + 256] = src[tid + 256];
    __syncthreads();
    const int p = tid & 31;
    const int r = tid >> 5;
    const float4* w = (const float4*)(W_in + (size_t)p * HID);
    float acc = 0.f;
#pragma unroll
    for (int k = 0; k < 64; ++k) {
        float4 hv = hid[r * 64 + k];
        float4 wv = w[k];
        acc += hv.x * wv.x + hv.y * wv.y + hv.z * wv.z + hv.w * wv.w;
    }
    const float val = acc + b_in[p];
    h[(size_t)(row0 + r) * PAi + p]  = val;
    hb[(size_t)(row0 + r) * PAi + p] = f2bf(val);
}

// -------- Kernel 2: t[b,j,o,q] = sum_p h[b,j,p] * W_out[o, p*32+q]  (bf16 out) --------
#define RMID 16
__global__ __launch_bounds__(256) void k_mid(const float* __restrict__ h,
                                             const float* __restrict__ W_out,
                                             ushort* __restrict__ t) {
    __shared__ __attribute__((aligned(16))) float hst[PAi][RMID];
    const int tid  = threadIdx.x;
    const int row0 = blockIdx.x * RMID;
    for (int s = tid; s < RMID * PAi; s += 256) {
        const int r = s >> 5, p = s & 31;
        hst[p][r] = h[(size_t)(row0 + r) * PAi + p];
    }
    __syncthreads();
    const int qg = tid & 7;
    const int o1 = tid >> 3;
    const float4* W4 = (const float4*)W_out;
    float4 accA[RMID], accB[RMID];
#pragma unroll
    for (int r = 0; r < RMID; ++r) {
        accA[r] = float4{0, 0, 0, 0};
        accB[r] = float4{0, 0, 0, 0};
    }
#pragma unroll 2
    for (int p = 0; p < PAi; ++p) {
        const float4 wa = W4[(o1 * PAi + p) * 8 + qg];
        const float4 wb = W4[((o1 + 32) * PAi + p) * 8 + qg];
#pragma unroll
        for (int r4 = 0; r4 < RMID / 4; ++r4) {
            const float4 h4 = *(const float4*)&hst[p][r4 * 4];
            const float hr[4] = {h4.x, h4.y, h4.z, h4.w};
#pragma unroll
            for (int e = 0; e < 4; ++e) {
                const int r = r4 * 4 + e;
                accA[r].x += hr[e] * wa.x; accA[r].y += hr[e] * wa.y;
                accA[r].z += hr[e] * wa.z; accA[r].w += hr[e] * wa.w;
                accB[r].x += hr[e] * wb.x; accB[r].y += hr[e] * wb.y;
                accB[r].z += hr[e] * wb.z; accB[r].w += hr[e] * wb.w;
            }
        }
    }
#pragma unroll
    for (int r = 0; r < RMID; ++r) {
        ushort4 ua, ub;
        ua.x = f2bf(accA[r].x); ua.y = f2bf(accA[r].y); ua.z = f2bf(accA[r].z); ua.w = f2bf(accA[r].w);
        ub.x = f2bf(accB[r].x); ub.y = f2bf(accB[r].y); ub.z = f2bf(accB[r].z); ub.w = f2bf(accB[r].w);
        ushort* dst = t + (size_t)(row0 + r) * OO * PAi;
        *(ushort4*)(dst + (o1 * 8 + qg) * 4)        = ua;
        *(ushort4*)(dst + ((o1 + 32) * 8 + qg) * 4) = ub;
    }
}

// -------- Kernel 3: MFMA + double-buffered LDS-transpose pipeline --------
// Per chunk of 256 jo: produce = {pw prefetch (4x float4), 4 t-frag loads, 4 MFMA, LDS write},
// consume = {LDS read i-rows, add bias+pw, 1KB-coalesced NT store}. One barrier per chunk;
// produce(c+1) is issued before consume(c), so HBM loads are always in flight.
#define SEG 4096
#define CH  256
#define NCH (SEG / CH)
#define LSTR 260
__global__ __launch_bounds__(256, 4) void k_out(const ushort* __restrict__ t,   // bf16 [B][L*OO][PAi]
                                                const ushort* __restrict__ hb,  // bf16 [B][L][PAi]
                                                const float* __restrict__ pw,
                                                const float* __restrict__ b_out,
                                                float* __restrict__ out) {
    __shared__ float sacc0[16 * LSTR];  // 16.6 KB
    __shared__ float sacc1[16 * LSTR];
    const int tid  = threadIdx.x;
    const int lane = tid & 63;
    const int wave = tid >> 6;
    const int b    = blockIdx.z;
    const int i0   = blockIdx.y * 16;
    const int seg0 = blockIdx.x * SEG;
    const int l15  = lane & 15;
    const int g    = lane >> 4;

    // B operand: h rows i0..i0+15 (n = l15, k = g*8+e)
    const bf16x8 hfrag = *(const bf16x8*)(hb + ((size_t)(b * LL + i0 + l15)) * PAi + g * 8);
    const f32x4 bo4 = *(const f32x4*)(b_out + ((lane * 4) & 63));
    const size_t outrow0 = ((size_t)(b * LL + i0)) * (LL * OO);

    auto produce = [&](int c, f32x4* pv, float* sbuf) {
        const int cbase = seg0 + c * CH;
#pragma unroll
        for (int rr = 0; rr < 4; ++rr) {
            const int row = wave * 4 + rr;
            pv[rr] = *(const f32x4*)(pw + outrow0 + (size_t)row * (LL * OO) + cbase + lane * 4);
        }
        const int wjo = cbase + wave * 64;
        const ushort* tb0 = t + ((size_t)b * LL * OO + wjo + l15) * PAi + g * 8;
#pragma unroll
        for (int tt = 0; tt < 4; ++tt) {
            const bf16x8 tfrag = *(const bf16x8*)(tb0 + (size_t)tt * (16 * PAi));
            f32x4 z = {0.f, 0.f, 0.f, 0.f};
            f32x4 a = __builtin_amdgcn_mfma_f32_16x16x32_bf16(tfrag, hfrag, z, 0, 0, 0);
            *(f32x4*)&sbuf[l15 * LSTR + wave * 64 + tt * 16 + g * 4] = a;
        }
    };
    auto consume = [&](int c, const f32x4* pv, const float* sbuf) {
        const int cbase = seg0 + c * CH;
#pragma unroll
        for (int rr = 0; rr < 4; ++rr) {
            const int row = wave * 4 + rr;
            const f32x4 a4 = *(const f32x4*)&sbuf[row * LSTR + lane * 4];
            f32x4 res = a4 + bo4 + pv[rr];
            __builtin_nontemporal_store(res,
                (f32x4*)(out + outrow0 + (size_t)row * (LL * OO) + cbase + lane * 4));
        }
    };

    f32x4 pvA[4], pvB[4];
    produce(0, pvA, sacc0);
    for (int c = 0; c < NCH; c += 2) {
        __syncthreads();                       // produce(c) -> sacc0 visible; consume(c-1) done
        if (c + 1 < NCH) produce(c + 1, pvB, sacc1);
        consume(c, pvA, sacc0);
        __syncthreads();                       // produce(c+1) -> sacc1 visible; consume(c) done
        if (c + 2 < NCH) produce(c + 2, pvA, sacc0);
        if (c + 1 < NCH) consume(c + 1, pvB, sacc1);
    }
}

extern "C" void kernel_launch(void* const* d_in, const int* in_sizes, int n_in,
                              void* d_out, int out_size, void* d_ws, size_t ws_size,
                              hipStream_t stream) {
    const float* hidden = (const float*)d_in[0];
    const float* pw     = (const float*)d_in[1];
    const float* W_in   = (const float*)d_in[2];
    const float* b_in   = (const float*)d_in[3];
    const float* W_out  = (const float*)d_in[4];
    const float* b_out  = (const float*)d_in[5];
    float* out = (float*)d_out;

    float*  h  = (float*)d_ws;                                // 65536 f32  (256 KB)
    ushort* hb = (ushort*)(h + (size_t)BB * LL * PAi);        // 65536 bf16 (128 KB)
    ushort* tb = hb + (size_t)BB * LL * PAi;                  // 4194304 bf16 (8 MB)

    k_in <<<dim3(BB * LL / 8), 256, 0, stream>>>(hidden, W_in, b_in, h, hb);
    k_mid<<<dim3(BB * LL / RMID), 256, 0, stream>>>(h, W_out, tb);
    // 8 jo-segments x 32 i-tiles x B = 1024 blocks = exactly 4/CU resident
    k_out<<<dim3(LL * OO / SEG, LL / 16, BB), 256, 0, stream>>>(tb, hb, pw, b_out, out);
}